// Round 9
// baseline (222.832 us; speedup 1.0000x reference)
//
#include <hip/hip_runtime.h>
#include <math.h>

#define BB 8
#define NN 512
#define DD 1024
#define HH 16
#define DH 64
#define INNER 1024
#define QKV3 3072
// attn head-plane stride in shorts: N*N + 64 (128B pad) breaks the exact
// 512KB power-of-2 stride that aliases all 16 head planes onto the same
// L2-set/HBM-channel group in the 16-plane gathers.
#define PSTR (NN * NN + 64)

typedef __attribute__((ext_vector_type(8))) short short8;
typedef __attribute__((ext_vector_type(4))) float f32x4;

#define AS1 __attribute__((address_space(1)))
#define AS3 __attribute__((address_space(3)))

__device__ __forceinline__ float4 ld4(const float* p) { return *(const float4*)p; }

__device__ __forceinline__ unsigned short f2bf(float f) {
    unsigned u = __float_as_uint(f);
    return (unsigned short)((u + 0x7fffu + ((u >> 16) & 1u)) >> 16);
}
__device__ __forceinline__ float bf2f(unsigned short u) {
    return __uint_as_float(((unsigned)u) << 16);
}

// ---------------------------------------------------------------------------
// Merged preprocessing: conv_bf16 + convT(w_qkv) + convT(w_out) in one launch.
// ---------------------------------------------------------------------------
__global__ void preprocess(const float* __restrict__ x, unsigned short* __restrict__ xb,
                           const float* __restrict__ wq, unsigned short* __restrict__ wqT,
                           const float* __restrict__ wo, unsigned short* __restrict__ woT) {
    __shared__ float t[32][33];
    const int tid = threadIdx.x;
    const int bx = blockIdx.x;
    if (bx < 4096) {
        size_t i = ((size_t)bx * 256 + tid) * 4;
        float4 v = ld4(x + i);
        ushort4 o;
        o.x = f2bf(v.x); o.y = f2bf(v.y); o.z = f2bf(v.z); o.w = f2bf(v.w);
        *(ushort4*)(xb + i) = o;
        return;
    }
    const float* in; unsigned short* out; int K, N, n0, k0;
    if (bx < 7168) {
        const int bb = bx - 4096;
        in = wq; out = wqT; K = DD; N = QKV3;
        n0 = (bb % 96) * 32; k0 = (bb / 96) * 32;
    } else {
        const int bb = bx - 7168;
        in = wo; out = woT; K = INNER; N = INNER;
        n0 = (bb & 31) * 32; k0 = (bb >> 5) * 32;
    }
    const int tx = tid & 31, ty = tid >> 5;  // 32 x 8
#pragma unroll
    for (int l = 0; l < 4; ++l)
        t[ty + 8 * l][tx] = in[(size_t)(k0 + ty + 8 * l) * N + n0 + tx];
    __syncthreads();
#pragma unroll
    for (int l = 0; l < 4; ++l)
        out[(size_t)(n0 + ty + 8 * l) * K + k0 + tx] = f2bf(t[tx][ty + 8 * l]);
}

// ---------------------------------------------------------------------------
// bf16 MFMA GEMM, fp32 out (+bias): C[M,N] = A[M,K] * Bt[N,K]^T   (128x128)
// 1-barrier-per-K-tile dbuf (R7-verified).  LDS 32KB.
// ---------------------------------------------------------------------------
__device__ __forceinline__ void stage128(const unsigned short* __restrict__ A,
                                         const unsigned short* __restrict__ Bt,
                                         int K, int bm, int bn, int kt,
                                         short* sb, int w, int l) {
#pragma unroll
    for (int t = 0; t < 2; ++t) {
        const int q = w * 2 + t;
        const int li = q * 512 + l * 8;
        const int row = li >> 5, kc = li & 31;
        __builtin_amdgcn_global_load_lds(
            (const AS1 void*)(A + (size_t)(bm + row) * K + kt * 32 + kc),
            (AS3 void*)(sb + q * 512), 16, 0, 0);
        __builtin_amdgcn_global_load_lds(
            (const AS1 void*)(Bt + (size_t)(bn + row) * K + kt * 32 + kc),
            (AS3 void*)(sb + 4096 + q * 512), 16, 0, 0);
    }
}

__global__ __launch_bounds__(256) void gemm_bf16(
    const unsigned short* __restrict__ A, const unsigned short* __restrict__ Bt,
    float* __restrict__ C, const float* __restrict__ bias, int M, int N, int K) {
    __shared__ __align__(16) short lds_[2 * 8192];   // 32KB
    const int tid = threadIdx.x;
    const int w = tid >> 6, l = tid & 63;
    const int bm = blockIdx.y * 128, bn = blockIdx.x * 128;
    const int wm = (w >> 1) * 64, wn = (w & 1) * 64;
    const int lrow = l & 15, lq = l >> 4;
    const int NT = K >> 5;

    f32x4 acc[4][4];
#pragma unroll
    for (int i = 0; i < 4; ++i)
#pragma unroll
        for (int j = 0; j < 4; ++j) acc[i][j] = (f32x4){0.f, 0.f, 0.f, 0.f};

    stage128(A, Bt, K, bm, bn, 0, lds_, w, l);
    asm volatile("s_waitcnt vmcnt(0)" ::: "memory");
    __builtin_amdgcn_s_barrier();

    for (int t = 0; t < NT; ++t) {
        const int s = t & 1;
        if (t + 1 < NT)
            stage128(A, Bt, K, bm, bn, t + 1, lds_ + (s ^ 1) * 8192, w, l);
        const short* As_ = lds_ + s * 8192;
        const short* Bs_ = As_ + 4096;
        short8 a[4], b[4];
#pragma unroll
        for (int i = 0; i < 4; ++i)
            a[i] = *(const short8*)(As_ + (wm + i * 16 + lrow) * 32 + lq * 8);
#pragma unroll
        for (int j = 0; j < 4; ++j)
            b[j] = *(const short8*)(Bs_ + (wn + j * 16 + lrow) * 32 + lq * 8);

        asm volatile("s_waitcnt lgkmcnt(0)" ::: "memory");
        __builtin_amdgcn_sched_barrier(0);

        __builtin_amdgcn_s_setprio(1);
#pragma unroll
        for (int i = 0; i < 4; ++i)
#pragma unroll
            for (int j = 0; j < 4; ++j)
                acc[i][j] = __builtin_amdgcn_mfma_f32_16x16x32_bf16(a[i], b[j], acc[i][j], 0, 0, 0);
        __builtin_amdgcn_s_setprio(0);

        asm volatile("s_waitcnt vmcnt(0)" ::: "memory");
        __builtin_amdgcn_s_barrier();
    }

#pragma unroll
    for (int i = 0; i < 4; ++i)
#pragma unroll
        for (int j = 0; j < 4; ++j) {
            const int col = bn + wn + j * 16 + lrow;
            const float bv = bias ? bias[col] : 0.f;
#pragma unroll
            for (int r = 0; r < 4; ++r) {
                const int row = bm + wm + i * 16 + lq * 4 + r;
                C[(size_t)row * N + col] = acc[i][j][r] + bv;
            }
        }
}

// ---------------------------------------------------------------------------
// QKV GEMM (R13-verified): 256x128-tile, bf16 out, 1-barrier dbuf, 384 blocks.
// ---------------------------------------------------------------------------
__device__ __forceinline__ void stage_st(const unsigned short* __restrict__ G, int K,
                                         int row0, int kt, short* dst_half,
                                         int w, int l) {
    const int grow = row0 + w * 16 + (l >> 2);
    const int gcol = kt * 32 + (((l & 3) * 8) ^ ((l & 32) ? 16 : 0));
    __builtin_amdgcn_global_load_lds(
        (const AS1 void*)(G + (size_t)grow * K + gcol),
        (AS3 void*)(dst_half + w * 512), 16, 0, 0);
}

__global__ __launch_bounds__(512, 4) void gemm256_bf(
    const unsigned short* __restrict__ A, const unsigned short* __restrict__ Bt,
    unsigned short* __restrict__ C, int M, int N, int K) {
    __shared__ __align__(16) short lds_[2 * 12288];   // 48KB
    const int tid = threadIdx.x;
    const int w = tid >> 6, l = tid & 63;
    const int wmi = w >> 1, wni = w & 1;        // 4M x 2N wave grid
    const int lrow = l & 15, lq = l >> 4;
    const int bm = blockIdx.y * 256, bn = blockIdx.x * 128;
    const int NT = K >> 5;                       // K-tiles of 32

    const int aoff = lrow * 32 + ((lq * 8) ^ ((lrow & 8) ? 16 : 0));

    f32x4 acc[4][4];
#pragma unroll
    for (int i = 0; i < 4; ++i)
#pragma unroll
        for (int j = 0; j < 4; ++j) acc[i][j] = (f32x4){0.f, 0.f, 0.f, 0.f};

    stage_st(A,  K, bm,       0, lds_ + 0,    w, l);
    stage_st(A,  K, bm + 128, 0, lds_ + 4096, w, l);
    stage_st(Bt, K, bn,       0, lds_ + 8192, w, l);
    asm volatile("s_waitcnt vmcnt(0)" ::: "memory");
    __builtin_amdgcn_s_barrier();

    for (int t = 0; t < NT; ++t) {
        const int s = t & 1;
        if (t + 1 < NT) {
            short* nb = lds_ + (s ^ 1) * 12288;
            stage_st(A,  K, bm,       t + 1, nb,        w, l);
            stage_st(A,  K, bm + 128, t + 1, nb + 4096, w, l);
            stage_st(Bt, K, bn,       t + 1, nb + 8192, w, l);
        }
        const short* cb = lds_ + s * 12288;
        short8 a[4], b[4];
#pragma unroll
        for (int i = 0; i < 4; ++i)
            a[i] = *(const short8*)(cb + (wmi * 4 + i) * 512 + aoff);
#pragma unroll
        for (int j = 0; j < 4; ++j)
            b[j] = *(const short8*)(cb + 8192 + (wni * 4 + j) * 512 + aoff);

        asm volatile("s_waitcnt lgkmcnt(0)" ::: "memory");
        __builtin_amdgcn_sched_barrier(0);   // rule #18: pin MFMA below the wait

        __builtin_amdgcn_s_setprio(1);
#pragma unroll
        for (int i = 0; i < 4; ++i)
#pragma unroll
            for (int j = 0; j < 4; ++j)
                acc[i][j] = __builtin_amdgcn_mfma_f32_16x16x32_bf16(a[i], b[j], acc[i][j], 0, 0, 0);
        __builtin_amdgcn_s_setprio(0);

        asm volatile("s_waitcnt vmcnt(0)" ::: "memory");
        __builtin_amdgcn_s_barrier();
    }

#pragma unroll
    for (int i = 0; i < 4; ++i)
#pragma unroll
        for (int j = 0; j < 4; ++j) {
            const int col = bn + wni * 64 + j * 16 + lrow;
#pragma unroll
            for (int r = 0; r < 4; ++r) {
                const int row = bm + wmi * 64 + i * 16 + lq * 4 + r;
                C[(size_t)row * N + col] = f2bf(acc[i][j][r]);
            }
        }
}

// ---------------------------------------------------------------------------
// Merged scores + V-transpose (R13-verified). 1-D grid 6144:
// [0,2048) scores (K-half LDS-staged, coalesced obuf flush, bh-fastest),
// [2048,6144) V transpose.
// ---------------------------------------------------------------------------
__global__ __launch_bounds__(256) void scores_tv(
    const unsigned short* __restrict__ qkvb, unsigned short* __restrict__ attnb,
    unsigned short* __restrict__ vT, float* __restrict__ lsum2) {
    __shared__ unsigned short sh[256 * 64 + 4 * 16 * 68];   // 41.2KB pool
    const int bx = blockIdx.x;
    const int tid = threadIdx.x;

    if (bx >= 2048) {
        const int t = bx - 2048;
        const int j0 = (t & 15) * 32;
        const int d0 = ((t >> 4) & 1) * 32;
        const int bh = t >> 5;
        const int h = bh & 15, b = bh >> 4;
        unsigned short (*tt)[33] = (unsigned short(*)[33])sh;
        const int tx = tid & 31, ty = tid >> 5;
        const unsigned short* src = qkvb + (size_t)(b * NN) * QKV3 + 2 * INNER + h * DH;
#pragma unroll
        for (int k = 0; k < 4; ++k)
            tt[ty + 8 * k][tx] = src[(size_t)(j0 + ty + 8 * k) * QKV3 + d0 + tx];
        __syncthreads();
        unsigned short* dst = vT + (size_t)bh * DH * NN;
#pragma unroll
        for (int k = 0; k < 4; ++k)
            dst[(size_t)(d0 + ty + 8 * k) * NN + j0 + tx] = tt[tx][ty + 8 * k];
        return;
    }

    unsigned short* Ks = sh;                          // [256*64]
    unsigned short* obuf = sh + 16384;                // [4][16][68]
    const int bh = bx & 127;
    const int h = bh & 15, b = bh >> 4;
    const int jh = (bx >> 7) & 1;
    const int w = tid >> 6, l = tid & 63;
    const int i0 = (bx >> 8) * 64 + w * 16;
    const int lrow = l & 15, lq = l >> 4;

    const unsigned short* kbase =
        qkvb + (size_t)(b * NN + jh * 256) * QKV3 + INNER + h * DH;
#pragma unroll
    for (int i = 0; i < 8; ++i) {
        const int r = (w * 8 + i) * 8 + (l >> 3);   // row this lane covers
        const int c = (l & 7) ^ (r & 7);            // inverse-swizzled chunk
        __builtin_amdgcn_global_load_lds(
            (const AS1 void*)(kbase + (size_t)r * QKV3 + c * 8),
            (AS3 void*)(Ks + (w * 8 + i) * 512), 16, 0, 0);
    }

    const unsigned short* qb = qkvb + (size_t)(b * NN) * QKV3 + h * DH + lq * 8;
    const short8 qf0 = *(const short8*)(qb + (size_t)(i0 + lrow) * QKV3);
    const short8 qf1 = *(const short8*)(qb + (size_t)(i0 + lrow) * QKV3 + 32);

    asm volatile("s_waitcnt vmcnt(0)" ::: "memory");
    __syncthreads();

    unsigned short* obase = attnb + (size_t)bh * PSTR + (size_t)i0 * NN + jh * 256;
    unsigned short* ob = obuf + (w * 16) * 68;
    const int sw = lrow & 7;                     // per-lane read swizzle
    float lacc = 0.f;
#pragma unroll
    for (int jt = 0; jt < 16; ++jt) {
        const int R = jt * 16 + lrow;
        const short8 kf0 = *(const short8*)(Ks + R * 64 + ((lq ^ sw) * 8));
        const short8 kf1 = *(const short8*)(Ks + R * 64 + (((4 + lq) ^ sw) * 8));
        f32x4 acc = (f32x4){0.f, 0.f, 0.f, 0.f};
        acc = __builtin_amdgcn_mfma_f32_16x16x32_bf16(kf0, qf0, acc, 0, 0, 0);
        acc = __builtin_amdgcn_mfma_f32_16x16x32_bf16(kf1, qf1, acc, 0, 0, 0);
        float e0 = __expf(acc[0] * 0.125f);
        float e1 = __expf(acc[1] * 0.125f);
        float e2 = __expf(acc[2] * 0.125f);
        float e3 = __expf(acc[3] * 0.125f);
        lacc += (e0 + e1) + (e2 + e3);
        ushort4 o;
        o.x = f2bf(e0); o.y = f2bf(e1); o.z = f2bf(e2); o.w = f2bf(e3);
        *(ushort4*)(ob + lrow * 68 + (jt & 3) * 16 + lq * 4) = o;
        if ((jt & 3) == 3) {
            const int jb = (jt >> 2) * 64;
#pragma unroll
            for (int q = 0; q < 4; ++q) {
                const int rr = q * 4 + (l >> 4);
                const int cc = l & 15;
                *(ushort4*)(obase + (size_t)rr * NN + jb + cc * 4) =
                    *(const ushort4*)(ob + rr * 68 + cc * 4);
            }
        }
    }
    lacc += __shfl_xor(lacc, 16, 64);
    lacc += __shfl_xor(lacc, 32, 64);
    if (lq == 0)
        lsum2[(size_t)jh * BB * HH * NN + (size_t)bh * NN + i0 + lrow] = lacc;
}

// ---------------------------------------------------------------------------
// FUSED re-attention + LN + PV (R14). Eliminates reattn's 67MB write and
// pv's 67MB read (the A' round-trip) plus one launch.
// Block = (b, 16-row i-tile): 256 blocks x 512 threads (8 waves); wave w owns
// output heads g = {2w, 2w+1} (acc 32 VGPR/lane). Per 64-j tile:
//  phase1: each thread owns (i = 2w+(l>>5), j = 2*(l&31)) -> reads E[h] for
//    all 16 h (prefetched to regs last phase; 32-lane-contiguous 4B loads),
//    Ē = E/lsum, M[g] = Σ_h w[h][g]Ē[h], LN over g, A' -> bf16 -> LDS tile
//    [16g][16i][8 chunks] with chunk XOR-swizzle key (i&7) (same involution
//    as the R7-verified pv Ps path).
//  phase2: prefetch E(jt+1); per g: pf = A'[g] frags from swizzled LDS
//    (2-way bank alias = free), vf = vT[bg][d][j] direct 16B global reads
//    (algebraically identical addresses to pv's staged-Vs reads), 16 MFMA.
// Epilogue: identical C-write mapping to the R7-verified pv_mfma.
// LDS 34.3KB.
// ---------------------------------------------------------------------------
__global__ __launch_bounds__(512) void reattn_pv(
    const unsigned short* __restrict__ attnb, const unsigned short* __restrict__ vT,
    const float* __restrict__ lsum2, const float* __restrict__ rw,
    const float* __restrict__ gamma, const float* __restrict__ beta,
    unsigned short* __restrict__ outhb) {
    __shared__ unsigned short Ash[16 * 16 * 64];   // 32KB A' tile (swizzled)
    __shared__ float wsh[16][16];
    __shared__ float linv[16][16];                 // [h][i]
    __shared__ float gsh[16], bsh[16];

    const int b = blockIdx.x >> 5;
    const int i0 = (blockIdx.x & 31) * 16;
    const int tid = threadIdx.x;
    const int w = tid >> 6, l = tid & 63;
    const int lrow = l & 15, lq = l >> 4;

    if (tid < 256) {
        ((float*)wsh)[tid] = rw[tid];
        const int h = tid >> 4, i = tid & 15;
        const float s =
            lsum2[(size_t)(b * HH + h) * NN + i0 + i] +
            lsum2[(size_t)BB * HH * NN + (size_t)(b * HH + h) * NN + i0 + i];
        linv[h][i] = 1.0f / s;
    }
    if (tid < 16) { gsh[tid] = gamma[tid]; bsh[tid] = beta[tid]; }

    // reattn-phase mapping: thread owns (ri, rj..rj+1)
    const int ri = w * 2 + (l >> 5);          // i row 0-15
    const int rj = (l & 31) * 2;              // even j within tile
    const unsigned short* ebase =
        attnb + (size_t)(b * HH) * PSTR + (size_t)(i0 + ri) * NN + rj;

    f32x4 acc[2][4];
#pragma unroll
    for (int gg = 0; gg < 2; ++gg)
#pragma unroll
        for (int dt = 0; dt < 4; ++dt) acc[gg][dt] = (f32x4){0.f, 0.f, 0.f, 0.f};

    unsigned e[16];
#pragma unroll
    for (int h = 0; h < 16; ++h)
        e[h] = *(const unsigned*)(ebase + (size_t)h * PSTR);

    __syncthreads();   // wsh/linv/gsh ready

    const int g0 = w * 2;
    const int cch = rj >> 3;                           // chunk 0-7
    const int csw = ((cch ^ (ri & 7)) << 3) + (rj & 7);  // swizzled short offset

    for (int jt = 0; jt < 8; ++jt) {
        // ---- phase 1: reattn + LN -> A' tile ----
        float e0[16], e1[16];
#pragma unroll
        for (int h = 0; h < 16; ++h) {
            const float li = linv[h][ri];
            e0[h] = bf2f((unsigned short)(e[h] & 0xffffu)) * li;
            e1[h] = bf2f((unsigned short)(e[h] >> 16)) * li;
        }
        float m0[16], m1[16];
        float mean0 = 0.f, mean1 = 0.f;
#pragma unroll
        for (int g = 0; g < 16; ++g) {
            float s0 = 0.f, s1 = 0.f;
#pragma unroll
            for (int h = 0; h < 16; ++h) {
                const float wg = wsh[h][g];
                s0 += e0[h] * wg; s1 += e1[h] * wg;
            }
            m0[g] = s0; m1[g] = s1;
            mean0 += s0; mean1 += s1;
        }
        mean0 *= 0.0625f; mean1 *= 0.0625f;
        float va0 = 0.f, va1 = 0.f;
#pragma unroll
        for (int g = 0; g < 16; ++g) {
            const float d0 = m0[g] - mean0, d1 = m1[g] - mean1;
            va0 += d0 * d0; va1 += d1 * d1;
        }
        const float ri0 = rsqrtf(va0 * 0.0625f + 1e-3f);
        const float ri1 = rsqrtf(va1 * 0.0625f + 1e-3f);
#pragma unroll
        for (int g = 0; g < 16; ++g) {
            const unsigned short a0 = f2bf((m0[g] - mean0) * ri0 * gsh[g] + bsh[g]);
            const unsigned short a1 = f2bf((m1[g] - mean1) * ri1 * gsh[g] + bsh[g]);
            *(unsigned*)(&Ash[(g * 16 + ri) * 64 + csw]) = ((unsigned)a1 << 16) | (unsigned)a0;
        }
        __syncthreads();

        // ---- phase 2: prefetch E(jt+1), MFMA ----
        if (jt < 7) {
#pragma unroll
            for (int h = 0; h < 16; ++h)
                e[h] = *(const unsigned*)(ebase + (size_t)h * PSTR + (jt + 1) * 64);
        }
        const int j0 = jt * 64;
#pragma unroll
        for (int gg = 0; gg < 2; ++gg) {
            const int g = g0 + gg;
            const unsigned short* vb = vT + (size_t)(b * HH + g) * DH * NN;
#pragma unroll
            for (int kc = 0; kc < 2; ++kc) {
                const int cc = kc * 4 + lq;
                const short8 pf = *(const short8*)(
                    &Ash[(g * 16 + lrow) * 64 + ((cc ^ (lrow & 7)) << 3)]);
#pragma unroll
                for (int dt = 0; dt < 4; ++dt) {
                    const short8 vf = *(const short8*)(
                        vb + (size_t)(dt * 16 + lrow) * NN + j0 + kc * 32 + lq * 8);
                    acc[gg][dt] = __builtin_amdgcn_mfma_f32_16x16x32_bf16(
                        vf, pf, acc[gg][dt], 0, 0, 0);
                }
            }
        }
        __syncthreads();
    }

    // ---- epilogue (same mapping as verified pv_mfma) ----
#pragma unroll
    for (int gg = 0; gg < 2; ++gg) {
        const int g = g0 + gg;
        unsigned short* orow = outhb +
            (size_t)(b * NN + i0 + lrow) * INNER + g * DH + lq * 4;
#pragma unroll
        for (int dt = 0; dt < 4; ++dt) {
            ushort4 o;
            o.x = f2bf(acc[gg][dt][0]); o.y = f2bf(acc[gg][dt][1]);
            o.z = f2bf(acc[gg][dt][2]); o.w = f2bf(acc[gg][dt][3]);
            *(ushort4*)(orow + dt * 16) = o;
        }
    }
}

// ---------------------------------------------------------------------------
extern "C" void kernel_launch(void* const* d_in, const int* in_sizes, int n_in,
                              void* d_out, int out_size, void* d_ws, size_t ws_size,
                              hipStream_t stream) {
    const float* x        = (const float*)d_in[0];
    const float* w_qkv    = (const float*)d_in[1];
    const float* reattn_w = (const float*)d_in[2];
    const float* ln_gamma = (const float*)d_in[3];
    const float* ln_beta  = (const float*)d_in[4];
    const float* w_out    = (const float*)d_in[5];
    const float* b_out    = (const float*)d_in[6];
    float* out = (float*)d_out;

    unsigned short* qkvb  = (unsigned short*)d_ws;                 // 12.58M
    unsigned short* attnb = qkvb + (size_t)BB * NN * QKV3;         // 128 * PSTR
    unsigned short* vTb   = attnb + (size_t)BB * HH * PSTR;        // 4.19M
    unsigned short* outhb = vTb + (size_t)BB * HH * DH * NN;       // 4.19M
    unsigned short* xb    = outhb + (size_t)BB * NN * INNER;       // 4.19M
    unsigned short* wqkvT = xb + (size_t)BB * NN * DD;             // 3.15M
    unsigned short* woutT = wqkvT + (size_t)DD * QKV3;             // 1.05M
    float*          lsum2 = (float*)(woutT + (size_t)INNER * INNER);  // 2*B*H*N f32

    dim3 blk(256);

    // merged conversions (1 launch)
    preprocess<<<dim3(8192), blk, 0, stream>>>(x, xb, w_qkv, wqkvT, w_out, woutT);

    // QKV projection -> bf16 (256x128-tile, 384 blocks, 2 resident/CU)
    gemm256_bf<<<dim3(QKV3 / 128, (BB * NN) / 256), dim3(512), 0, stream>>>(
        xb, wqkvT, qkvb, BB * NN, QKV3, DD);

    // merged scores + V-transpose (both depend only on qkvb)
    scores_tv<<<dim3(6144), blk, 0, stream>>>(qkvb, attnb, vTb, lsum2);

    // fused re-attention + LN + PV (eliminates the A' round-trip)
    reattn_pv<<<dim3(BB * 32), dim3(512), 0, stream>>>(
        attnb, vTb, lsum2, reattn_w, ln_gamma, ln_beta, outhb);

    // output projection + bias (fp32 out; 1-barrier dbuf)
    gemm_bf16<<<dim3(INNER / 128, (BB * NN) / 128), blk, 0, stream>>>(
        outhb, woutT, out, b_out, BB * NN, INNER, INNER);
}

// Round 10
// 219.473 us; speedup vs baseline: 1.0153x; 1.0153x over previous
//
#include <hip/hip_runtime.h>
#include <math.h>

#define BB 8
#define NN 512
#define DD 1024
#define HH 16
#define DH 64
#define INNER 1024
#define QKV3 3072
// attn head-plane stride in shorts: N*N + 64 (128B pad) breaks the exact
// 512KB power-of-2 stride that aliases all 16 head planes onto the same
// L2-set/HBM-channel group in the 16-plane gathers.
#define PSTR (NN * NN + 64)

typedef __attribute__((ext_vector_type(8))) short short8;
typedef __attribute__((ext_vector_type(4))) float f32x4;

#define AS1 __attribute__((address_space(1)))
#define AS3 __attribute__((address_space(3)))

__device__ __forceinline__ float4 ld4(const float* p) { return *(const float4*)p; }

__device__ __forceinline__ unsigned short f2bf(float f) {
    unsigned u = __float_as_uint(f);
    return (unsigned short)((u + 0x7fffu + ((u >> 16) & 1u)) >> 16);
}
__device__ __forceinline__ float bf2f(unsigned short u) {
    return __uint_as_float(((unsigned)u) << 16);
}

// ---------------------------------------------------------------------------
// Merged preprocessing: conv_bf16 + convT(w_qkv) + convT(w_out) in one launch.
// ---------------------------------------------------------------------------
__global__ void preprocess(const float* __restrict__ x, unsigned short* __restrict__ xb,
                           const float* __restrict__ wq, unsigned short* __restrict__ wqT,
                           const float* __restrict__ wo, unsigned short* __restrict__ woT) {
    __shared__ float t[32][33];
    const int tid = threadIdx.x;
    const int bx = blockIdx.x;
    if (bx < 4096) {
        size_t i = ((size_t)bx * 256 + tid) * 4;
        float4 v = ld4(x + i);
        ushort4 o;
        o.x = f2bf(v.x); o.y = f2bf(v.y); o.z = f2bf(v.z); o.w = f2bf(v.w);
        *(ushort4*)(xb + i) = o;
        return;
    }
    const float* in; unsigned short* out; int K, N, n0, k0;
    if (bx < 7168) {
        const int bb = bx - 4096;
        in = wq; out = wqT; K = DD; N = QKV3;
        n0 = (bb % 96) * 32; k0 = (bb / 96) * 32;
    } else {
        const int bb = bx - 7168;
        in = wo; out = woT; K = INNER; N = INNER;
        n0 = (bb & 31) * 32; k0 = (bb >> 5) * 32;
    }
    const int tx = tid & 31, ty = tid >> 5;  // 32 x 8
#pragma unroll
    for (int l = 0; l < 4; ++l)
        t[ty + 8 * l][tx] = in[(size_t)(k0 + ty + 8 * l) * N + n0 + tx];
    __syncthreads();
#pragma unroll
    for (int l = 0; l < 4; ++l)
        out[(size_t)(n0 + ty + 8 * l) * K + k0 + tx] = f2bf(t[tx][ty + 8 * l]);
}

// ---------------------------------------------------------------------------
// bf16 MFMA GEMM, fp32 out (+bias): C[M,N] = A[M,K] * Bt[N,K]^T   (128x128)
// 1-barrier-per-K-tile dbuf (R7-verified).  LDS 32KB.
// ---------------------------------------------------------------------------
__device__ __forceinline__ void stage128(const unsigned short* __restrict__ A,
                                         const unsigned short* __restrict__ Bt,
                                         int K, int bm, int bn, int kt,
                                         short* sb, int w, int l) {
#pragma unroll
    for (int t = 0; t < 2; ++t) {
        const int q = w * 2 + t;
        const int li = q * 512 + l * 8;
        const int row = li >> 5, kc = li & 31;
        __builtin_amdgcn_global_load_lds(
            (const AS1 void*)(A + (size_t)(bm + row) * K + kt * 32 + kc),
            (AS3 void*)(sb + q * 512), 16, 0, 0);
        __builtin_amdgcn_global_load_lds(
            (const AS1 void*)(Bt + (size_t)(bn + row) * K + kt * 32 + kc),
            (AS3 void*)(sb + 4096 + q * 512), 16, 0, 0);
    }
}

__global__ __launch_bounds__(256) void gemm_bf16(
    const unsigned short* __restrict__ A, const unsigned short* __restrict__ Bt,
    float* __restrict__ C, const float* __restrict__ bias, int M, int N, int K) {
    __shared__ __align__(16) short lds_[2 * 8192];   // 32KB
    const int tid = threadIdx.x;
    const int w = tid >> 6, l = tid & 63;
    const int bm = blockIdx.y * 128, bn = blockIdx.x * 128;
    const int wm = (w >> 1) * 64, wn = (w & 1) * 64;
    const int lrow = l & 15, lq = l >> 4;
    const int NT = K >> 5;

    f32x4 acc[4][4];
#pragma unroll
    for (int i = 0; i < 4; ++i)
#pragma unroll
        for (int j = 0; j < 4; ++j) acc[i][j] = (f32x4){0.f, 0.f, 0.f, 0.f};

    stage128(A, Bt, K, bm, bn, 0, lds_, w, l);
    asm volatile("s_waitcnt vmcnt(0)" ::: "memory");
    __builtin_amdgcn_s_barrier();

    for (int t = 0; t < NT; ++t) {
        const int s = t & 1;
        if (t + 1 < NT)
            stage128(A, Bt, K, bm, bn, t + 1, lds_ + (s ^ 1) * 8192, w, l);
        const short* As_ = lds_ + s * 8192;
        const short* Bs_ = As_ + 4096;
        short8 a[4], b[4];
#pragma unroll
        for (int i = 0; i < 4; ++i)
            a[i] = *(const short8*)(As_ + (wm + i * 16 + lrow) * 32 + lq * 8);
#pragma unroll
        for (int j = 0; j < 4; ++j)
            b[j] = *(const short8*)(Bs_ + (wn + j * 16 + lrow) * 32 + lq * 8);

        asm volatile("s_waitcnt lgkmcnt(0)" ::: "memory");
        __builtin_amdgcn_sched_barrier(0);

        __builtin_amdgcn_s_setprio(1);
#pragma unroll
        for (int i = 0; i < 4; ++i)
#pragma unroll
            for (int j = 0; j < 4; ++j)
                acc[i][j] = __builtin_amdgcn_mfma_f32_16x16x32_bf16(a[i], b[j], acc[i][j], 0, 0, 0);
        __builtin_amdgcn_s_setprio(0);

        asm volatile("s_waitcnt vmcnt(0)" ::: "memory");
        __builtin_amdgcn_s_barrier();
    }

#pragma unroll
    for (int i = 0; i < 4; ++i)
#pragma unroll
        for (int j = 0; j < 4; ++j) {
            const int col = bn + wn + j * 16 + lrow;
            const float bv = bias ? bias[col] : 0.f;
#pragma unroll
            for (int r = 0; r < 4; ++r) {
                const int row = bm + wm + i * 16 + lq * 4 + r;
                C[(size_t)row * N + col] = acc[i][j][r] + bv;
            }
        }
}

// ---------------------------------------------------------------------------
// QKV GEMM (R13-verified): 256x128-tile, bf16 out, 1-barrier dbuf, 384 blocks.
// ---------------------------------------------------------------------------
__device__ __forceinline__ void stage_st(const unsigned short* __restrict__ G, int K,
                                         int row0, int kt, short* dst_half,
                                         int w, int l) {
    const int grow = row0 + w * 16 + (l >> 2);
    const int gcol = kt * 32 + (((l & 3) * 8) ^ ((l & 32) ? 16 : 0));
    __builtin_amdgcn_global_load_lds(
        (const AS1 void*)(G + (size_t)grow * K + gcol),
        (AS3 void*)(dst_half + w * 512), 16, 0, 0);
}

__global__ __launch_bounds__(512, 4) void gemm256_bf(
    const unsigned short* __restrict__ A, const unsigned short* __restrict__ Bt,
    unsigned short* __restrict__ C, int M, int N, int K) {
    __shared__ __align__(16) short lds_[2 * 12288];   // 48KB
    const int tid = threadIdx.x;
    const int w = tid >> 6, l = tid & 63;
    const int wmi = w >> 1, wni = w & 1;        // 4M x 2N wave grid
    const int lrow = l & 15, lq = l >> 4;
    const int bm = blockIdx.y * 256, bn = blockIdx.x * 128;
    const int NT = K >> 5;                       // K-tiles of 32

    const int aoff = lrow * 32 + ((lq * 8) ^ ((lrow & 8) ? 16 : 0));

    f32x4 acc[4][4];
#pragma unroll
    for (int i = 0; i < 4; ++i)
#pragma unroll
        for (int j = 0; j < 4; ++j) acc[i][j] = (f32x4){0.f, 0.f, 0.f, 0.f};

    stage_st(A,  K, bm,       0, lds_ + 0,    w, l);
    stage_st(A,  K, bm + 128, 0, lds_ + 4096, w, l);
    stage_st(Bt, K, bn,       0, lds_ + 8192, w, l);
    asm volatile("s_waitcnt vmcnt(0)" ::: "memory");
    __builtin_amdgcn_s_barrier();

    for (int t = 0; t < NT; ++t) {
        const int s = t & 1;
        if (t + 1 < NT) {
            short* nb = lds_ + (s ^ 1) * 12288;
            stage_st(A,  K, bm,       t + 1, nb,        w, l);
            stage_st(A,  K, bm + 128, t + 1, nb + 4096, w, l);
            stage_st(Bt, K, bn,       t + 1, nb + 8192, w, l);
        }
        const short* cb = lds_ + s * 12288;
        short8 a[4], b[4];
#pragma unroll
        for (int i = 0; i < 4; ++i)
            a[i] = *(const short8*)(cb + (wmi * 4 + i) * 512 + aoff);
#pragma unroll
        for (int j = 0; j < 4; ++j)
            b[j] = *(const short8*)(cb + 8192 + (wni * 4 + j) * 512 + aoff);

        asm volatile("s_waitcnt lgkmcnt(0)" ::: "memory");
        __builtin_amdgcn_sched_barrier(0);   // rule #18: pin MFMA below the wait

        __builtin_amdgcn_s_setprio(1);
#pragma unroll
        for (int i = 0; i < 4; ++i)
#pragma unroll
            for (int j = 0; j < 4; ++j)
                acc[i][j] = __builtin_amdgcn_mfma_f32_16x16x32_bf16(a[i], b[j], acc[i][j], 0, 0, 0);
        __builtin_amdgcn_s_setprio(0);

        asm volatile("s_waitcnt vmcnt(0)" ::: "memory");
        __builtin_amdgcn_s_barrier();
    }

#pragma unroll
    for (int i = 0; i < 4; ++i)
#pragma unroll
        for (int j = 0; j < 4; ++j) {
            const int col = bn + wni * 64 + j * 16 + lrow;
#pragma unroll
            for (int r = 0; r < 4; ++r) {
                const int row = bm + wmi * 64 + i * 16 + lq * 4 + r;
                C[(size_t)row * N + col] = f2bf(acc[i][j][r]);
            }
        }
}

// ---------------------------------------------------------------------------
// Merged scores + V-transpose (R13-verified). 1-D grid 6144:
// [0,2048) scores (K-half LDS-staged, coalesced obuf flush, bh-fastest),
// [2048,6144) V transpose.
// ---------------------------------------------------------------------------
__global__ __launch_bounds__(256) void scores_tv(
    const unsigned short* __restrict__ qkvb, unsigned short* __restrict__ attnb,
    unsigned short* __restrict__ vT, float* __restrict__ lsum2) {
    __shared__ unsigned short sh[256 * 64 + 4 * 16 * 68];   // 41.2KB pool
    const int bx = blockIdx.x;
    const int tid = threadIdx.x;

    if (bx >= 2048) {
        const int t = bx - 2048;
        const int j0 = (t & 15) * 32;
        const int d0 = ((t >> 4) & 1) * 32;
        const int bh = t >> 5;
        const int h = bh & 15, b = bh >> 4;
        unsigned short (*tt)[33] = (unsigned short(*)[33])sh;
        const int tx = tid & 31, ty = tid >> 5;
        const unsigned short* src = qkvb + (size_t)(b * NN) * QKV3 + 2 * INNER + h * DH;
#pragma unroll
        for (int k = 0; k < 4; ++k)
            tt[ty + 8 * k][tx] = src[(size_t)(j0 + ty + 8 * k) * QKV3 + d0 + tx];
        __syncthreads();
        unsigned short* dst = vT + (size_t)bh * DH * NN;
#pragma unroll
        for (int k = 0; k < 4; ++k)
            dst[(size_t)(d0 + ty + 8 * k) * NN + j0 + tx] = tt[tx][ty + 8 * k];
        return;
    }

    unsigned short* Ks = sh;                          // [256*64]
    unsigned short* obuf = sh + 16384;                // [4][16][68]
    const int bh = bx & 127;
    const int h = bh & 15, b = bh >> 4;
    const int jh = (bx >> 7) & 1;
    const int w = tid >> 6, l = tid & 63;
    const int i0 = (bx >> 8) * 64 + w * 16;
    const int lrow = l & 15, lq = l >> 4;

    const unsigned short* kbase =
        qkvb + (size_t)(b * NN + jh * 256) * QKV3 + INNER + h * DH;
#pragma unroll
    for (int i = 0; i < 8; ++i) {
        const int r = (w * 8 + i) * 8 + (l >> 3);   // row this lane covers
        const int c = (l & 7) ^ (r & 7);            // inverse-swizzled chunk
        __builtin_amdgcn_global_load_lds(
            (const AS1 void*)(kbase + (size_t)r * QKV3 + c * 8),
            (AS3 void*)(Ks + (w * 8 + i) * 512), 16, 0, 0);
    }

    const unsigned short* qb = qkvb + (size_t)(b * NN) * QKV3 + h * DH + lq * 8;
    const short8 qf0 = *(const short8*)(qb + (size_t)(i0 + lrow) * QKV3);
    const short8 qf1 = *(const short8*)(qb + (size_t)(i0 + lrow) * QKV3 + 32);

    asm volatile("s_waitcnt vmcnt(0)" ::: "memory");
    __syncthreads();

    unsigned short* obase = attnb + (size_t)bh * PSTR + (size_t)i0 * NN + jh * 256;
    unsigned short* ob = obuf + (w * 16) * 68;
    const int sw = lrow & 7;                     // per-lane read swizzle
    float lacc = 0.f;
#pragma unroll
    for (int jt = 0; jt < 16; ++jt) {
        const int R = jt * 16 + lrow;
        const short8 kf0 = *(const short8*)(Ks + R * 64 + ((lq ^ sw) * 8));
        const short8 kf1 = *(const short8*)(Ks + R * 64 + (((4 + lq) ^ sw) * 8));
        f32x4 acc = (f32x4){0.f, 0.f, 0.f, 0.f};
        acc = __builtin_amdgcn_mfma_f32_16x16x32_bf16(kf0, qf0, acc, 0, 0, 0);
        acc = __builtin_amdgcn_mfma_f32_16x16x32_bf16(kf1, qf1, acc, 0, 0, 0);
        float e0 = __expf(acc[0] * 0.125f);
        float e1 = __expf(acc[1] * 0.125f);
        float e2 = __expf(acc[2] * 0.125f);
        float e3 = __expf(acc[3] * 0.125f);
        lacc += (e0 + e1) + (e2 + e3);
        ushort4 o;
        o.x = f2bf(e0); o.y = f2bf(e1); o.z = f2bf(e2); o.w = f2bf(e3);
        *(ushort4*)(ob + lrow * 68 + (jt & 3) * 16 + lq * 4) = o;
        if ((jt & 3) == 3) {
            const int jb = (jt >> 2) * 64;
#pragma unroll
            for (int q = 0; q < 4; ++q) {
                const int rr = q * 4 + (l >> 4);
                const int cc = l & 15;
                *(ushort4*)(obase + (size_t)rr * NN + jb + cc * 4) =
                    *(const ushort4*)(ob + rr * 68 + cc * 4);
            }
        }
    }
    lacc += __shfl_xor(lacc, 16, 64);
    lacc += __shfl_xor(lacc, 32, 64);
    if (lq == 0)
        lsum2[(size_t)jh * BB * HH * NN + (size_t)bh * NN + i0 + lrow] = lacc;
}

// ---------------------------------------------------------------------------
// FUSED re-attention + LN + PV v2 (R15). Math/indexing identical to the
// R14-verified version (passed); only load SCHEDULING restructured:
//  - vf loads hoisted into an explicit vfr[16] register array before the
//    MFMA cluster (R14: VGPR=68 proved the compiler couldn't hoist -> each
//    MFMA serially ate ~200cyc L2 latency).
//  - E(jt+1) prefetch moved to the TOP of phase 1 with an explicit
//    ecur/enxt ping-pong (rule #20-safe static copy) -> covered by the
//    whole VALU phase + barrier + MFMA phase instead of just MFMA.
//  - XCD remap b = bx&7: all 32 blocks of a batch share one L2's V[b] (1MB).
// ---------------------------------------------------------------------------
__global__ __launch_bounds__(512) void reattn_pv(
    const unsigned short* __restrict__ attnb, const unsigned short* __restrict__ vT,
    const float* __restrict__ lsum2, const float* __restrict__ rw,
    const float* __restrict__ gamma, const float* __restrict__ beta,
    unsigned short* __restrict__ outhb) {
    __shared__ unsigned short Ash[16 * 16 * 64];   // 32KB A' tile (swizzled)
    __shared__ float wsh[16][16];
    __shared__ float linv[16][16];                 // [h][i]
    __shared__ float gsh[16], bsh[16];

    const int b = blockIdx.x & 7;                  // XCD-locality: same-b same-XCD
    const int i0 = (blockIdx.x >> 3) * 16;
    const int tid = threadIdx.x;
    const int w = tid >> 6, l = tid & 63;
    const int lrow = l & 15, lq = l >> 4;

    if (tid < 256) {
        ((float*)wsh)[tid] = rw[tid];
        const int h = tid >> 4, i = tid & 15;
        const float s =
            lsum2[(size_t)(b * HH + h) * NN + i0 + i] +
            lsum2[(size_t)BB * HH * NN + (size_t)(b * HH + h) * NN + i0 + i];
        linv[h][i] = 1.0f / s;
    }
    if (tid < 16) { gsh[tid] = gamma[tid]; bsh[tid] = beta[tid]; }

    // reattn-phase mapping: thread owns (ri, rj..rj+1)
    const int ri = w * 2 + (l >> 5);          // i row 0-15
    const int rj = (l & 31) * 2;              // even j within tile
    const unsigned short* ebase =
        attnb + (size_t)(b * HH) * PSTR + (size_t)(i0 + ri) * NN + rj;

    f32x4 acc[2][4];
#pragma unroll
    for (int gg = 0; gg < 2; ++gg)
#pragma unroll
        for (int dt = 0; dt < 4; ++dt) acc[gg][dt] = (f32x4){0.f, 0.f, 0.f, 0.f};

    unsigned ecur[16];
#pragma unroll
    for (int h = 0; h < 16; ++h)
        ecur[h] = *(const unsigned*)(ebase + (size_t)h * PSTR);

    __syncthreads();   // wsh/linv/gsh ready

    const int g0 = w * 2;
    const int cch = rj >> 3;                           // chunk 0-7
    const int csw = ((cch ^ (ri & 7)) << 3) + (rj & 7);  // swizzled short offset

    for (int jt = 0; jt < 8; ++jt) {
        // ---- phase 1: unpack E, issue next-jt prefetch EARLY, reattn+LN ----
        float e0[16], e1[16];
#pragma unroll
        for (int h = 0; h < 16; ++h) {
            const float li = linv[h][ri];
            e0[h] = bf2f((unsigned short)(ecur[h] & 0xffffu)) * li;
            e1[h] = bf2f((unsigned short)(ecur[h] >> 16)) * li;
        }
        unsigned enxt[16];
        if (jt < 7) {
#pragma unroll
            for (int h = 0; h < 16; ++h)
                enxt[h] = *(const unsigned*)(ebase + (size_t)h * PSTR + (jt + 1) * 64);
        }
        float m0[16], m1[16];
        float mean0 = 0.f, mean1 = 0.f;
#pragma unroll
        for (int g = 0; g < 16; ++g) {
            float s0 = 0.f, s1 = 0.f;
#pragma unroll
            for (int h = 0; h < 16; ++h) {
                const float wg = wsh[h][g];
                s0 += e0[h] * wg; s1 += e1[h] * wg;
            }
            m0[g] = s0; m1[g] = s1;
            mean0 += s0; mean1 += s1;
        }
        mean0 *= 0.0625f; mean1 *= 0.0625f;
        float va0 = 0.f, va1 = 0.f;
#pragma unroll
        for (int g = 0; g < 16; ++g) {
            const float d0 = m0[g] - mean0, d1 = m1[g] - mean1;
            va0 += d0 * d0; va1 += d1 * d1;
        }
        const float ri0 = rsqrtf(va0 * 0.0625f + 1e-3f);
        const float ri1 = rsqrtf(va1 * 0.0625f + 1e-3f);
#pragma unroll
        for (int g = 0; g < 16; ++g) {
            const unsigned short a0 = f2bf((m0[g] - mean0) * ri0 * gsh[g] + bsh[g]);
            const unsigned short a1 = f2bf((m1[g] - mean1) * ri1 * gsh[g] + bsh[g]);
            *(unsigned*)(&Ash[(g * 16 + ri) * 64 + csw]) = ((unsigned)a1 << 16) | (unsigned)a0;
        }
        __syncthreads();

        // ---- phase 2: hoisted vf loads, then MFMA cluster ----
        const int j0 = jt * 64;
        short8 vfr[16];
#pragma unroll
        for (int gg = 0; gg < 2; ++gg) {
            const unsigned short* vb = vT + (size_t)(b * HH + g0 + gg) * DH * NN;
#pragma unroll
            for (int kc = 0; kc < 2; ++kc)
#pragma unroll
                for (int dt = 0; dt < 4; ++dt)
                    vfr[gg * 8 + kc * 4 + dt] = *(const short8*)(
                        vb + (size_t)(dt * 16 + lrow) * NN + j0 + kc * 32 + lq * 8);
        }
#pragma unroll
        for (int gg = 0; gg < 2; ++gg) {
            const int g = g0 + gg;
#pragma unroll
            for (int kc = 0; kc < 2; ++kc) {
                const int cc = kc * 4 + lq;
                const short8 pf = *(const short8*)(
                    &Ash[(g * 16 + lrow) * 64 + ((cc ^ (lrow & 7)) << 3)]);
#pragma unroll
                for (int dt = 0; dt < 4; ++dt)
                    acc[gg][dt] = __builtin_amdgcn_mfma_f32_16x16x32_bf16(
                        vfr[gg * 8 + kc * 4 + dt], pf, acc[gg][dt], 0, 0, 0);
            }
        }
        __syncthreads();

        if (jt < 7) {
#pragma unroll
            for (int h = 0; h < 16; ++h) ecur[h] = enxt[h];
        }
    }

    // ---- epilogue (same mapping as verified pv_mfma) ----
#pragma unroll
    for (int gg = 0; gg < 2; ++gg) {
        const int g = g0 + gg;
        unsigned short* orow = outhb +
            (size_t)(b * NN + i0 + lrow) * INNER + g * DH + lq * 4;
#pragma unroll
        for (int dt = 0; dt < 4; ++dt) {
            ushort4 o;
            o.x = f2bf(acc[gg][dt][0]); o.y = f2bf(acc[gg][dt][1]);
            o.z = f2bf(acc[gg][dt][2]); o.w = f2bf(acc[gg][dt][3]);
            *(ushort4*)(orow + dt * 16) = o;
        }
    }
}

// ---------------------------------------------------------------------------
extern "C" void kernel_launch(void* const* d_in, const int* in_sizes, int n_in,
                              void* d_out, int out_size, void* d_ws, size_t ws_size,
                              hipStream_t stream) {
    const float* x        = (const float*)d_in[0];
    const float* w_qkv    = (const float*)d_in[1];
    const float* reattn_w = (const float*)d_in[2];
    const float* ln_gamma = (const float*)d_in[3];
    const float* ln_beta  = (const float*)d_in[4];
    const float* w_out    = (const float*)d_in[5];
    const float* b_out    = (const float*)d_in[6];
    float* out = (float*)d_out;

    unsigned short* qkvb  = (unsigned short*)d_ws;                 // 12.58M
    unsigned short* attnb = qkvb + (size_t)BB * NN * QKV3;         // 128 * PSTR
    unsigned short* vTb   = attnb + (size_t)BB * HH * PSTR;        // 4.19M
    unsigned short* outhb = vTb + (size_t)BB * HH * DH * NN;       // 4.19M
    unsigned short* xb    = outhb + (size_t)BB * NN * INNER;       // 4.19M
    unsigned short* wqkvT = xb + (size_t)BB * NN * DD;             // 3.15M
    unsigned short* woutT = wqkvT + (size_t)DD * QKV3;             // 1.05M
    float*          lsum2 = (float*)(woutT + (size_t)INNER * INNER);  // 2*B*H*N f32

    dim3 blk(256);

    // merged conversions (1 launch)
    preprocess<<<dim3(8192), blk, 0, stream>>>(x, xb, w_qkv, wqkvT, w_out, woutT);

    // QKV projection -> bf16 (256x128-tile, 384 blocks, 2 resident/CU)
    gemm256_bf<<<dim3(QKV3 / 128, (BB * NN) / 256), dim3(512), 0, stream>>>(
        xb, wqkvT, qkvb, BB * NN, QKV3, DD);

    // merged scores + V-transpose (both depend only on qkvb)
    scores_tv<<<dim3(6144), blk, 0, stream>>>(qkvb, attnb, vTb, lsum2);

    // fused re-attention + LN + PV (eliminates the A' round-trip)
    reattn_pv<<<dim3(BB * 32), dim3(512), 0, stream>>>(
        attnb, vTb, lsum2, reattn_w, ln_gamma, ln_beta, outhb);

    // output projection + bias (fp32 out; 1-barrier dbuf)
    gemm_bf16<<<dim3(INNER / 128, (BB * NN) / 128), blk, 0, stream>>>(
        outhb, woutT, out, b_out, BB * NN, INNER, INNER);
}

// Round 13
// 203.458 us; speedup vs baseline: 1.0952x; 1.0787x over previous
//
#include <hip/hip_runtime.h>
#include <math.h>

#define BB 8
#define NN 512
#define DD 1024
#define HH 16
#define DH 64
#define INNER 1024
#define QKV3 3072
// attn head-plane stride in shorts: N*N + 64 (128B pad) breaks the exact
// 512KB power-of-2 stride that aliases all 16 head planes onto the same
// L2-set/HBM-channel group in the 16-plane gathers.
#define PSTR (NN * NN + 64)

typedef __attribute__((ext_vector_type(8))) short short8;
typedef __attribute__((ext_vector_type(4))) float f32x4;

#define AS1 __attribute__((address_space(1)))
#define AS3 __attribute__((address_space(3)))

__device__ __forceinline__ float4 ld4(const float* p) { return *(const float4*)p; }

__device__ __forceinline__ unsigned short f2bf(float f) {
    unsigned u = __float_as_uint(f);
    return (unsigned short)((u + 0x7fffu + ((u >> 16) & 1u)) >> 16);
}
__device__ __forceinline__ float bf2f(unsigned short u) {
    return __uint_as_float(((unsigned)u) << 16);
}

// ---------------------------------------------------------------------------
// Merged preprocessing: conv_bf16 + convT(w_qkv) + convT(w_out) in one launch.
// ---------------------------------------------------------------------------
__global__ void preprocess(const float* __restrict__ x, unsigned short* __restrict__ xb,
                           const float* __restrict__ wq, unsigned short* __restrict__ wqT,
                           const float* __restrict__ wo, unsigned short* __restrict__ woT) {
    __shared__ float t[32][33];
    const int tid = threadIdx.x;
    const int bx = blockIdx.x;
    if (bx < 4096) {
        size_t i = ((size_t)bx * 256 + tid) * 4;
        float4 v = ld4(x + i);
        ushort4 o;
        o.x = f2bf(v.x); o.y = f2bf(v.y); o.z = f2bf(v.z); o.w = f2bf(v.w);
        *(ushort4*)(xb + i) = o;
        return;
    }
    const float* in; unsigned short* out; int K, N, n0, k0;
    if (bx < 7168) {
        const int bb = bx - 4096;
        in = wq; out = wqT; K = DD; N = QKV3;
        n0 = (bb % 96) * 32; k0 = (bb / 96) * 32;
    } else {
        const int bb = bx - 7168;
        in = wo; out = woT; K = INNER; N = INNER;
        n0 = (bb & 31) * 32; k0 = (bb >> 5) * 32;
    }
    const int tx = tid & 31, ty = tid >> 5;  // 32 x 8
#pragma unroll
    for (int l = 0; l < 4; ++l)
        t[ty + 8 * l][tx] = in[(size_t)(k0 + ty + 8 * l) * N + n0 + tx];
    __syncthreads();
#pragma unroll
    for (int l = 0; l < 4; ++l)
        out[(size_t)(n0 + ty + 8 * l) * K + k0 + tx] = f2bf(t[tx][ty + 8 * l]);
}

// ---------------------------------------------------------------------------
// bf16 MFMA GEMM, fp32 out (+bias): C[M,N] = A[M,K] * Bt[N,K]^T   (128x128)
// 1-barrier-per-K-tile dbuf (R7-verified).  LDS 32KB.
// ---------------------------------------------------------------------------
__device__ __forceinline__ void stage128(const unsigned short* __restrict__ A,
                                         const unsigned short* __restrict__ Bt,
                                         int K, int bm, int bn, int kt,
                                         short* sb, int w, int l) {
#pragma unroll
    for (int t = 0; t < 2; ++t) {
        const int q = w * 2 + t;
        const int li = q * 512 + l * 8;
        const int row = li >> 5, kc = li & 31;
        __builtin_amdgcn_global_load_lds(
            (const AS1 void*)(A + (size_t)(bm + row) * K + kt * 32 + kc),
            (AS3 void*)(sb + q * 512), 16, 0, 0);
        __builtin_amdgcn_global_load_lds(
            (const AS1 void*)(Bt + (size_t)(bn + row) * K + kt * 32 + kc),
            (AS3 void*)(sb + 4096 + q * 512), 16, 0, 0);
    }
}

__global__ __launch_bounds__(256) void gemm_bf16(
    const unsigned short* __restrict__ A, const unsigned short* __restrict__ Bt,
    float* __restrict__ C, const float* __restrict__ bias, int M, int N, int K) {
    __shared__ __align__(16) short lds_[2 * 8192];   // 32KB
    const int tid = threadIdx.x;
    const int w = tid >> 6, l = tid & 63;
    const int bm = blockIdx.y * 128, bn = blockIdx.x * 128;
    const int wm = (w >> 1) * 64, wn = (w & 1) * 64;
    const int lrow = l & 15, lq = l >> 4;
    const int NT = K >> 5;

    f32x4 acc[4][4];
#pragma unroll
    for (int i = 0; i < 4; ++i)
#pragma unroll
        for (int j = 0; j < 4; ++j) acc[i][j] = (f32x4){0.f, 0.f, 0.f, 0.f};

    stage128(A, Bt, K, bm, bn, 0, lds_, w, l);
    asm volatile("s_waitcnt vmcnt(0)" ::: "memory");
    __builtin_amdgcn_s_barrier();

    for (int t = 0; t < NT; ++t) {
        const int s = t & 1;
        if (t + 1 < NT)
            stage128(A, Bt, K, bm, bn, t + 1, lds_ + (s ^ 1) * 8192, w, l);
        const short* As_ = lds_ + s * 8192;
        const short* Bs_ = As_ + 4096;
        short8 a[4], b[4];
#pragma unroll
        for (int i = 0; i < 4; ++i)
            a[i] = *(const short8*)(As_ + (wm + i * 16 + lrow) * 32 + lq * 8);
#pragma unroll
        for (int j = 0; j < 4; ++j)
            b[j] = *(const short8*)(Bs_ + (wn + j * 16 + lrow) * 32 + lq * 8);

        asm volatile("s_waitcnt lgkmcnt(0)" ::: "memory");
        __builtin_amdgcn_sched_barrier(0);

        __builtin_amdgcn_s_setprio(1);
#pragma unroll
        for (int i = 0; i < 4; ++i)
#pragma unroll
            for (int j = 0; j < 4; ++j)
                acc[i][j] = __builtin_amdgcn_mfma_f32_16x16x32_bf16(a[i], b[j], acc[i][j], 0, 0, 0);
        __builtin_amdgcn_s_setprio(0);

        asm volatile("s_waitcnt vmcnt(0)" ::: "memory");
        __builtin_amdgcn_s_barrier();
    }

#pragma unroll
    for (int i = 0; i < 4; ++i)
#pragma unroll
        for (int j = 0; j < 4; ++j) {
            const int col = bn + wn + j * 16 + lrow;
            const float bv = bias ? bias[col] : 0.f;
#pragma unroll
            for (int r = 0; r < 4; ++r) {
                const int row = bm + wm + i * 16 + lq * 4 + r;
                C[(size_t)row * N + col] = acc[i][j][r] + bv;
            }
        }
}

// ---------------------------------------------------------------------------
// QKV GEMM (R13-verified): 256x128-tile, bf16 out, 1-barrier dbuf, 384 blocks.
// ---------------------------------------------------------------------------
__device__ __forceinline__ void stage_st(const unsigned short* __restrict__ G, int K,
                                         int row0, int kt, short* dst_half,
                                         int w, int l) {
    const int grow = row0 + w * 16 + (l >> 2);
    const int gcol = kt * 32 + (((l & 3) * 8) ^ ((l & 32) ? 16 : 0));
    __builtin_amdgcn_global_load_lds(
        (const AS1 void*)(G + (size_t)grow * K + gcol),
        (AS3 void*)(dst_half + w * 512), 16, 0, 0);
}

__global__ __launch_bounds__(512, 4) void gemm256_bf(
    const unsigned short* __restrict__ A, const unsigned short* __restrict__ Bt,
    unsigned short* __restrict__ C, int M, int N, int K) {
    __shared__ __align__(16) short lds_[2 * 12288];   // 48KB
    const int tid = threadIdx.x;
    const int w = tid >> 6, l = tid & 63;
    const int wmi = w >> 1, wni = w & 1;        // 4M x 2N wave grid
    const int lrow = l & 15, lq = l >> 4;
    const int bm = blockIdx.y * 256, bn = blockIdx.x * 128;
    const int NT = K >> 5;                       // K-tiles of 32

    const int aoff = lrow * 32 + ((lq * 8) ^ ((lrow & 8) ? 16 : 0));

    f32x4 acc[4][4];
#pragma unroll
    for (int i = 0; i < 4; ++i)
#pragma unroll
        for (int j = 0; j < 4; ++j) acc[i][j] = (f32x4){0.f, 0.f, 0.f, 0.f};

    stage_st(A,  K, bm,       0, lds_ + 0,    w, l);
    stage_st(A,  K, bm + 128, 0, lds_ + 4096, w, l);
    stage_st(Bt, K, bn,       0, lds_ + 8192, w, l);
    asm volatile("s_waitcnt vmcnt(0)" ::: "memory");
    __builtin_amdgcn_s_barrier();

    for (int t = 0; t < NT; ++t) {
        const int s = t & 1;
        if (t + 1 < NT) {
            short* nb = lds_ + (s ^ 1) * 12288;
            stage_st(A,  K, bm,       t + 1, nb,        w, l);
            stage_st(A,  K, bm + 128, t + 1, nb + 4096, w, l);
            stage_st(Bt, K, bn,       t + 1, nb + 8192, w, l);
        }
        const short* cb = lds_ + s * 12288;
        short8 a[4], b[4];
#pragma unroll
        for (int i = 0; i < 4; ++i)
            a[i] = *(const short8*)(cb + (wmi * 4 + i) * 512 + aoff);
#pragma unroll
        for (int j = 0; j < 4; ++j)
            b[j] = *(const short8*)(cb + 8192 + (wni * 4 + j) * 512 + aoff);

        asm volatile("s_waitcnt lgkmcnt(0)" ::: "memory");
        __builtin_amdgcn_sched_barrier(0);   // rule #18: pin MFMA below the wait

        __builtin_amdgcn_s_setprio(1);
#pragma unroll
        for (int i = 0; i < 4; ++i)
#pragma unroll
            for (int j = 0; j < 4; ++j)
                acc[i][j] = __builtin_amdgcn_mfma_f32_16x16x32_bf16(a[i], b[j], acc[i][j], 0, 0, 0);
        __builtin_amdgcn_s_setprio(0);

        asm volatile("s_waitcnt vmcnt(0)" ::: "memory");
        __builtin_amdgcn_s_barrier();
    }

#pragma unroll
    for (int i = 0; i < 4; ++i)
#pragma unroll
        for (int j = 0; j < 4; ++j) {
            const int col = bn + wni * 64 + j * 16 + lrow;
#pragma unroll
            for (int r = 0; r < 4; ++r) {
                const int row = bm + wmi * 64 + i * 16 + lq * 4 + r;
                C[(size_t)row * N + col] = f2bf(acc[i][j][r]);
            }
        }
}

// ---------------------------------------------------------------------------
// Merged scores + V-transpose (R13-verified). 1-D grid 6144:
// [0,2048) scores (K-half LDS-staged, coalesced obuf flush, bh-fastest),
// [2048,6144) V transpose.
// ---------------------------------------------------------------------------
__global__ __launch_bounds__(256) void scores_tv(
    const unsigned short* __restrict__ qkvb, unsigned short* __restrict__ attnb,
    unsigned short* __restrict__ vT, float* __restrict__ lsum2) {
    __shared__ unsigned short sh[256 * 64 + 4 * 16 * 68];   // 41.2KB pool
    const int bx = blockIdx.x;
    const int tid = threadIdx.x;

    if (bx >= 2048) {
        const int t = bx - 2048;
        const int j0 = (t & 15) * 32;
        const int d0 = ((t >> 4) & 1) * 32;
        const int bh = t >> 5;
        const int h = bh & 15, b = bh >> 4;
        unsigned short (*tt)[33] = (unsigned short(*)[33])sh;
        const int tx = tid & 31, ty = tid >> 5;
        const unsigned short* src = qkvb + (size_t)(b * NN) * QKV3 + 2 * INNER + h * DH;
#pragma unroll
        for (int k = 0; k < 4; ++k)
            tt[ty + 8 * k][tx] = src[(size_t)(j0 + ty + 8 * k) * QKV3 + d0 + tx];
        __syncthreads();
        unsigned short* dst = vT + (size_t)bh * DH * NN;
#pragma unroll
        for (int k = 0; k < 4; ++k)
            dst[(size_t)(d0 + ty + 8 * k) * NN + j0 + tx] = tt[tx][ty + 8 * k];
        return;
    }

    unsigned short* Ks = sh;                          // [256*64]
    unsigned short* obuf = sh + 16384;                // [4][16][68]
    const int bh = bx & 127;
    const int h = bh & 15, b = bh >> 4;
    const int jh = (bx >> 7) & 1;
    const int w = tid >> 6, l = tid & 63;
    const int i0 = (bx >> 8) * 64 + w * 16;
    const int lrow = l & 15, lq = l >> 4;

    const unsigned short* kbase =
        qkvb + (size_t)(b * NN + jh * 256) * QKV3 + INNER + h * DH;
#pragma unroll
    for (int i = 0; i < 8; ++i) {
        const int r = (w * 8 + i) * 8 + (l >> 3);   // row this lane covers
        const int c = (l & 7) ^ (r & 7);            // inverse-swizzled chunk
        __builtin_amdgcn_global_load_lds(
            (const AS1 void*)(kbase + (size_t)r * QKV3 + c * 8),
            (AS3 void*)(Ks + (w * 8 + i) * 512), 16, 0, 0);
    }

    const unsigned short* qb = qkvb + (size_t)(b * NN) * QKV3 + h * DH + lq * 8;
    const short8 qf0 = *(const short8*)(qb + (size_t)(i0 + lrow) * QKV3);
    const short8 qf1 = *(const short8*)(qb + (size_t)(i0 + lrow) * QKV3 + 32);

    asm volatile("s_waitcnt vmcnt(0)" ::: "memory");
    __syncthreads();

    unsigned short* obase = attnb + (size_t)bh * PSTR + (size_t)i0 * NN + jh * 256;
    unsigned short* ob = obuf + (w * 16) * 68;
    const int sw = lrow & 7;                     // per-lane read swizzle
    float lacc = 0.f;
#pragma unroll
    for (int jt = 0; jt < 16; ++jt) {
        const int R = jt * 16 + lrow;
        const short8 kf0 = *(const short8*)(Ks + R * 64 + ((lq ^ sw) * 8));
        const short8 kf1 = *(const short8*)(Ks + R * 64 + (((4 + lq) ^ sw) * 8));
        f32x4 acc = (f32x4){0.f, 0.f, 0.f, 0.f};
        acc = __builtin_amdgcn_mfma_f32_16x16x32_bf16(kf0, qf0, acc, 0, 0, 0);
        acc = __builtin_amdgcn_mfma_f32_16x16x32_bf16(kf1, qf1, acc, 0, 0, 0);
        float e0 = __expf(acc[0] * 0.125f);
        float e1 = __expf(acc[1] * 0.125f);
        float e2 = __expf(acc[2] * 0.125f);
        float e3 = __expf(acc[3] * 0.125f);
        lacc += (e0 + e1) + (e2 + e3);
        ushort4 o;
        o.x = f2bf(e0); o.y = f2bf(e1); o.z = f2bf(e2); o.w = f2bf(e3);
        *(ushort4*)(ob + lrow * 68 + (jt & 3) * 16 + lq * 4) = o;
        if ((jt & 3) == 3) {
            const int jb = (jt >> 2) * 64;
#pragma unroll
            for (int q = 0; q < 4; ++q) {
                const int rr = q * 4 + (l >> 4);
                const int cc = l & 15;
                *(ushort4*)(obase + (size_t)rr * NN + jb + cc * 4) =
                    *(const ushort4*)(ob + rr * 68 + cc * 4);
            }
        }
    }
    lacc += __shfl_xor(lacc, 16, 64);
    lacc += __shfl_xor(lacc, 32, 64);
    if (lq == 0)
        lsum2[(size_t)jh * BB * HH * NN + (size_t)bh * NN + i0 + lrow] = lacc;
}

// ---------------------------------------------------------------------------
// Re-attention + LN over heads, bf16 in/out (fp32 math), 4 j per thread.
// ---------------------------------------------------------------------------
__global__ void reattn_ln_bf(unsigned short* __restrict__ attnb,
                             const float* __restrict__ lsum2,
                             const float* __restrict__ rw,
                             const float* __restrict__ gamma,
                             const float* __restrict__ beta) {
    __shared__ float w[16][16];
    __shared__ float gs[16], bs[16];
    const int tid = threadIdx.x;
    ((float*)w)[tid] = rw[tid];
    if (tid < 16) { gs[tid] = gamma[tid]; bs[tid] = beta[tid]; }
    __syncthreads();

    const size_t idx = (size_t)blockIdx.x * 256 + tid;  // over B*N*N/4
    const int j4 = (int)(idx & 127);
    const int i = (int)((idx >> 7) & 511);
    const int b = (int)(idx >> 16);
    unsigned short* base = attnb + (size_t)(b * HH) * PSTR + (size_t)i * NN + j4 * 4;
    const float* l0 = lsum2 + (size_t)(b * HH) * NN + i;
    const float* l1 = l0 + (size_t)BB * HH * NN;

    float v[16][4];
#pragma unroll
    for (int h = 0; h < 16; ++h) {
        const float linv = 1.0f / (l0[h * NN] + l1[h * NN]);
        ushort4 u = *(const ushort4*)(base + (size_t)h * PSTR);
        v[h][0] = bf2f(u.x) * linv; v[h][1] = bf2f(u.y) * linv;
        v[h][2] = bf2f(u.z) * linv; v[h][3] = bf2f(u.w) * linv;
    }
    float o[16][4];
    float me[4] = {0.f, 0.f, 0.f, 0.f};
#pragma unroll
    for (int g = 0; g < 16; ++g) {
        float s0 = 0.f, s1 = 0.f, s2 = 0.f, s3 = 0.f;
#pragma unroll
        for (int h = 0; h < 16; ++h) {
            const float wg = w[h][g];
            s0 += v[h][0] * wg; s1 += v[h][1] * wg;
            s2 += v[h][2] * wg; s3 += v[h][3] * wg;
        }
        o[g][0] = s0; o[g][1] = s1; o[g][2] = s2; o[g][3] = s3;
        me[0] += s0; me[1] += s1; me[2] += s2; me[3] += s3;
    }
#pragma unroll
    for (int r = 0; r < 4; ++r) me[r] *= 0.0625f;
    float va[4] = {0.f, 0.f, 0.f, 0.f};
#pragma unroll
    for (int g = 0; g < 16; ++g)
#pragma unroll
        for (int r = 0; r < 4; ++r) {
            float d = o[g][r] - me[r];
            va[r] += d * d;
        }
    float ri[4];
#pragma unroll
    for (int r = 0; r < 4; ++r) ri[r] = rsqrtf(va[r] * 0.0625f + 1e-3f);
#pragma unroll
    for (int g = 0; g < 16; ++g) {
        ushort4 u;
        u.x = f2bf((o[g][0] - me[0]) * ri[0] * gs[g] + bs[g]);
        u.y = f2bf((o[g][1] - me[1]) * ri[1] * gs[g] + bs[g]);
        u.z = f2bf((o[g][2] - me[2]) * ri[2] * gs[g] + bs[g]);
        u.w = f2bf((o[g][3] - me[3]) * ri[3] * gs[g] + bs[g]);
        *(ushort4*)(base + (size_t)g * PSTR) = u;
    }
}

// ---------------------------------------------------------------------------
// PV MFMA: 1-barrier-per-j-step dbuf (R8-verified). LDS 48KB.
// XCD-locality grid: bh = blockIdx.x.
// ---------------------------------------------------------------------------
__device__ __forceinline__ void stage_pv(const unsigned short* __restrict__ pb,
                                         const unsigned short* __restrict__ vb,
                                         int j0, short* Ps, short* Vs,
                                         int w, int l, int lr8, int swd) {
#pragma unroll
    for (int t = 0; t < 4; ++t) {
        int c = w * 4 + t;
        int r = c * 8 + lr8;
        __builtin_amdgcn_global_load_lds(
            (const AS1 void*)(pb + (size_t)r * NN + j0 + swd),
            (AS3 void*)(Ps + c * 512), 16, 0, 0);
    }
#pragma unroll
    for (int t = 0; t < 2; ++t) {
        int c = w * 2 + t;
        int d = c * 8 + lr8;
        __builtin_amdgcn_global_load_lds(
            (const AS1 void*)(vb + (size_t)d * NN + j0 + swd),
            (AS3 void*)(Vs + c * 512), 16, 0, 0);
    }
}

__global__ __launch_bounds__(256) void pv_mfma(
    const unsigned short* __restrict__ attnb, const unsigned short* __restrict__ vT,
    unsigned short* __restrict__ outhb) {
    const int bh = blockIdx.x;
    const int h = bh & 15, b = bh >> 4;
    const int i0 = blockIdx.y * 128;
    __shared__ __align__(16) short Ps[2][128 * 64];   // 32KB
    __shared__ __align__(16) short Vs[2][64 * 64];    // 16KB
    const int tid = threadIdx.x;
    const int w = tid >> 6, l = tid & 63;
    const int lrow = l & 15, lq = l >> 4;
    const int lr8 = l >> 3;
    const int swd = ((l & 7) ^ (lr8 & 7)) * 8;

    f32x4 acc[2][4];
#pragma unroll
    for (int ic = 0; ic < 2; ++ic)
#pragma unroll
        for (int dt = 0; dt < 4; ++dt) acc[ic][dt] = (f32x4){0.f, 0.f, 0.f, 0.f};

    const unsigned short* pb = attnb + (size_t)bh * PSTR + (size_t)i0 * NN;
    const unsigned short* vb = vT + (size_t)bh * DH * NN;

    stage_pv(pb, vb, 0, Ps[0], Vs[0], w, l, lr8, swd);
    asm volatile("s_waitcnt vmcnt(0)" ::: "memory");
    __builtin_amdgcn_s_barrier();

    for (int js = 0; js < 8; ++js) {
        const int s = js & 1;
        if (js + 1 < 8)
            stage_pv(pb, vb, (js + 1) * 64, Ps[s ^ 1], Vs[s ^ 1], w, l, lr8, swd);

        short8 vf[8], pf[4];
#pragma unroll
        for (int kh = 0; kh < 2; ++kh) {
#pragma unroll
            for (int dt = 0; dt < 4; ++dt)
                vf[kh * 4 + dt] = *(const short8*)(
                    &Vs[s][(dt * 16 + lrow) * 64 + (((kh * 4 + lq) ^ (lrow & 7)) * 8)]);
#pragma unroll
            for (int ic = 0; ic < 2; ++ic)
                pf[kh * 2 + ic] = *(const short8*)(
                    &Ps[s][(w * 32 + ic * 16 + lrow) * 64 + (((kh * 4 + lq) ^ (lrow & 7)) * 8)]);
        }

        asm volatile("s_waitcnt lgkmcnt(0)" ::: "memory");
        __builtin_amdgcn_sched_barrier(0);

        __builtin_amdgcn_s_setprio(1);
#pragma unroll
        for (int kh = 0; kh < 2; ++kh)
#pragma unroll
            for (int ic = 0; ic < 2; ++ic)
#pragma unroll
                for (int dt = 0; dt < 4; ++dt)
                    acc[ic][dt] = __builtin_amdgcn_mfma_f32_16x16x32_bf16(
                        vf[kh * 4 + dt], pf[kh * 2 + ic], acc[ic][dt], 0, 0, 0);
        __builtin_amdgcn_s_setprio(0);

        asm volatile("s_waitcnt vmcnt(0)" ::: "memory");
        __builtin_amdgcn_s_barrier();
    }

#pragma unroll
    for (int ic = 0; ic < 2; ++ic) {
        unsigned short* orow = outhb +
            ((size_t)(b * NN + i0 + w * 32 + ic * 16 + lrow)) * INNER + h * DH + lq * 4;
#pragma unroll
        for (int dt = 0; dt < 4; ++dt) {
            ushort4 o;
            o.x = f2bf(acc[ic][dt][0]); o.y = f2bf(acc[ic][dt][1]);
            o.z = f2bf(acc[ic][dt][2]); o.w = f2bf(acc[ic][dt][3]);
            *(ushort4*)(orow + dt * 16) = o;
        }
    }
}

// ---------------------------------------------------------------------------
extern "C" void kernel_launch(void* const* d_in, const int* in_sizes, int n_in,
                              void* d_out, int out_size, void* d_ws, size_t ws_size,
                              hipStream_t stream) {
    const float* x        = (const float*)d_in[0];
    const float* w_qkv    = (const float*)d_in[1];
    const float* reattn_w = (const float*)d_in[2];
    const float* ln_gamma = (const float*)d_in[3];
    const float* ln_beta  = (const float*)d_in[4];
    const float* w_out    = (const float*)d_in[5];
    const float* b_out    = (const float*)d_in[6];
    float* out = (float*)d_out;

    unsigned short* qkvb  = (unsigned short*)d_ws;                 // 12.58M
    unsigned short* attnb = qkvb + (size_t)BB * NN * QKV3;         // 128 * PSTR
    unsigned short* vTb   = attnb + (size_t)BB * HH * PSTR;        // 4.19M
    unsigned short* outhb = vTb + (size_t)BB * HH * DH * NN;       // 4.19M
    unsigned short* xb    = outhb + (size_t)BB * NN * INNER;       // 4.19M
    unsigned short* wqkvT = xb + (size_t)BB * NN * DD;             // 3.15M
    unsigned short* woutT = wqkvT + (size_t)DD * QKV3;             // 1.05M
    float*          lsum2 = (float*)(woutT + (size_t)INNER * INNER);  // 2*B*H*N f32

    dim3 blk(256);

    // merged conversions (1 launch)
    preprocess<<<dim3(8192), blk, 0, stream>>>(x, xb, w_qkv, wqkvT, w_out, woutT);

    // QKV projection -> bf16 (256x128-tile, 384 blocks, 2 resident/CU)
    gemm256_bf<<<dim3(QKV3 / 128, (BB * NN) / 256), dim3(512), 0, stream>>>(
        xb, wqkvT, qkvb, BB * NN, QKV3, DD);

    // merged scores + V-transpose (both depend only on qkvb)
    scores_tv<<<dim3(6144), blk, 0, stream>>>(qkvb, attnb, vTb, lsum2);

    // re-attention + LN (normalizes by 1/(l0+l1) on load, in-place bf16)
    reattn_ln_bf<<<dim3((BB * NN * NN) / 1024), blk, 0, stream>>>(
        attnb, lsum2, reattn_w, ln_gamma, ln_beta);

    // P @ V -> outh bf16 (bh fastest for vT L2 locality; 1-barrier dbuf)
    pv_mfma<<<dim3(BB * HH, NN / 128), blk, 0, stream>>>(attnb, vTb, outhb);

    // output projection + bias (fp32 out; 1-barrier dbuf)
    gemm_bf16<<<dim3(INNER / 128, (BB * NN) / 128), blk, 0, stream>>>(
        outhb, woutT, out, b_out, BB * NN, INNER, INNER);
}